// Round 7
// baseline (306.036 us; speedup 1.0000x reference)
//
#include <hip/hip_runtime.h>

// Scaled dot-product attention, B=2 H=12 S=4096 d=64, fp32 in/out.
// Round 7 = Round 6 + epilogue fix: rowsum inverse must be indexed by the
// accO element's q-ROW (accO C-layout col = d), not by lane&31 (= d). Round 6
// divided by the wrong row's softmax sum -> absmax 0.139. Inverse now routed
// through sInv[q] in LDS, as rounds 4-5 did.
// Design (round 6): split-K waves (wave = q-pair x key-half), P kept in
// registers via half-wave shfl_xor(32) exchange, fragment-ordered K/V images
// staged by global_load_lds, double-buffered, one barrier per tile.
// Layouts (m74/m101, verified rounds 3-5):
//  A 32x32x16: A[m=lane&31][k=8*(lane>>5)+j]; B: B[k=8*(lane>>5)+j][n=lane&31]
//  C/D: col=lane&31, row=(reg&3)+8*(reg>>2)+4*(lane>>5)

constexpr int Sseq = 4096;
constexpr int Dh   = 64;
constexpr int BM   = 128;         // q rows per block (2 q-pairs x 2 subtiles x 32)
constexpr int BN   = 64;          // keys per K-tile (2 waves x 32)
constexpr int NT   = Sseq / BN;   // 64 key-tiles per head

typedef short bf16x8 __attribute__((ext_vector_type(8)));
typedef float f32x4  __attribute__((ext_vector_type(4)));
typedef float f32x16 __attribute__((ext_vector_type(16)));

__device__ __forceinline__ unsigned short f2bf(float x) {
    union { float f; unsigned int u; } v; v.f = x;
    unsigned int r = v.u + 0x7fffu + ((v.u >> 16) & 1u);  // RNE
    return (unsigned short)(r >> 16);
}

// pack two f32 -> bf16x2 (a -> low16, b -> high16), round-half-up
__device__ __forceinline__ unsigned int packbf2(float a, float b) {
    unsigned int ua = __float_as_uint(a) + 0x8000u;
    unsigned int ub = __float_as_uint(b) + 0x8000u;
    return __builtin_amdgcn_perm(ub, ua, 0x07060302u);
}

#define EXP2(x) exp2f(x)

__device__ __forceinline__ void gld16(const void* g, void* l) {
    __builtin_amdgcn_global_load_lds(
        (const __attribute__((address_space(1))) void*)g,
        (__attribute__((address_space(3))) void*)l, 16, 0, 0);
}

union u4bf8 { uint4 u; bf16x8 v; };

// ---------------- pre-pass: fragment-ordered bf16 images ---------------------
// ws per (bh,kb): 16 chunks x 1024 B. Chunks 0-7 = K, 8-15 = V^T.
// K chunk (mt*4+kc), lane slot l: K[key=32mt+(l&31)][d=16kc+8*(l>>5)+0..7]
// V chunk (nt*4+kv), lane slot l: V^T[d=32nt+(l&31)][key=16kv+8*(l>>5)+0..7]
// Output slot s = chunk*64+l is written linearly -> coalesced uint4 stores.
__global__ __launch_bounds__(256)
void preconv_kernel(const float* __restrict__ K, const float* __restrict__ V,
                    unsigned short* __restrict__ ws)
{
    const int kb = blockIdx.x, bh = blockIdx.y, tid = threadIdx.x;
    const float* Kb = K + ((size_t)bh * Sseq + kb * BN) * Dh;
    const float* Vb = V + ((size_t)bh * Sseq + kb * BN) * Dh;
    unsigned short* img = ws + (size_t)(bh * NT + kb) * 8192;

    #pragma unroll
    for (int it = 0; it < 4; ++it) {
        const int s = it * 256 + tid;
        const int chunk = s >> 6, l = s & 63;
        uint4 o;
        if (chunk < 8) {
            const int key = 32 * (chunk >> 2) + (l & 31);
            const int d0  = 16 * (chunk & 3) + 8 * (l >> 5);
            const float4 a = *reinterpret_cast<const float4*>(Kb + key * Dh + d0);
            const float4 b = *reinterpret_cast<const float4*>(Kb + key * Dh + d0 + 4);
            o.x = packbf2(a.x, a.y); o.y = packbf2(a.z, a.w);
            o.z = packbf2(b.x, b.y); o.w = packbf2(b.z, b.w);
        } else {
            const int c8   = chunk - 8;
            const int d    = 32 * (c8 >> 2) + (l & 31);
            const int key0 = 16 * (c8 & 3) + 8 * (l >> 5);
            float p[8];
            #pragma unroll
            for (int j = 0; j < 8; ++j) p[j] = Vb[(key0 + j) * Dh + d];
            o.x = packbf2(p[0], p[1]); o.y = packbf2(p[2], p[3]);
            o.z = packbf2(p[4], p[5]); o.w = packbf2(p[6], p[7]);
        }
        *reinterpret_cast<uint4*>(img + s * 8) = o;
    }
}

// ---------------- main flash-attention kernel --------------------------------
__global__ __launch_bounds__(256, 2)
void fattn_kernel(const float* __restrict__ Q, const unsigned short* __restrict__ ws,
                  float* __restrict__ O)
{
    __shared__ unsigned short sKV[2][8192];   // dbuf: [K 8KB | V^T 8KB], frag order
    __shared__ float sR[2][2][32];            // cross-wave rowsum exchange
    __shared__ float sInv[2][2][32];          // per-q inverse (epilogue)

    const int tid  = threadIdx.x;
    const int wave = tid >> 6;
    const int lane = tid & 63;
    const int lo32 = lane & 31;
    const int h    = lane >> 5;   // half-wave 0/1
    const int qp2  = wave >> 1;   // q-pair 0/1 (q rows qp2*64 .. +63)
    const int mtw  = wave & 1;    // key-half 0/1 (keys mtw*32 .. +31)

    const int qblk = blockIdx.x;  // 0..31
    const int bh   = blockIdx.y;  // 0..23

    const float* gQ = Q + (size_t)bh * Sseq * Dh;
    float*       gO = O + (size_t)bh * Sseq * Dh;

    // Q as B-operand of S^T = K.Q^T: lane holds Q[q=lo32][d = 16kc + 8h + j]
    const float qscale = 0.18033688011112042f;  // (1/sqrt(64)) * log2(e)
    bf16x8 qf[2][4];
    #pragma unroll
    for (int u = 0; u < 2; ++u) {
        const int qrow = qblk * BM + qp2 * 64 + u * 32 + lo32;
        const float* qp = gQ + (size_t)qrow * Dh + h * 8;
        #pragma unroll
        for (int kc = 0; kc < 4; ++kc) {
            float4 a = *reinterpret_cast<const float4*>(qp + kc * 16);
            float4 b = *reinterpret_cast<const float4*>(qp + kc * 16 + 4);
            qf[u][kc][0] = (short)f2bf(a.x * qscale);
            qf[u][kc][1] = (short)f2bf(a.y * qscale);
            qf[u][kc][2] = (short)f2bf(a.z * qscale);
            qf[u][kc][3] = (short)f2bf(a.w * qscale);
            qf[u][kc][4] = (short)f2bf(b.x * qscale);
            qf[u][kc][5] = (short)f2bf(b.y * qscale);
            qf[u][kc][6] = (short)f2bf(b.z * qscale);
            qf[u][kc][7] = (short)f2bf(b.w * qscale);
        }
    }

    f32x16 accO[2][2];   // [subtile][d-half]; partial over this wave's 32 keys
    #pragma unroll
    for (int u = 0; u < 2; ++u)
        #pragma unroll
        for (int nt = 0; nt < 2; ++nt)
            #pragma unroll
            for (int i = 0; i < 16; ++i) accO[u][nt][i] = 0.f;
    float rsum[2] = {0.f, 0.f};  // per-lane, q = lo32, this wave's key-half

    const char* img = (const char*)(ws + (size_t)bh * NT * 8192);
    const int loff = lane * 16;
    const int woff = wave * 4096;

    // prologue: DMA tile 0 -> buf 0 (each wave stages 4 KB)
    #pragma unroll
    for (int c = 0; c < 4; ++c)
        gld16(img + woff + c * 1024 + loff, (char*)sKV[0] + woff + c * 1024);
    __syncthreads();

    for (int kb = 0; kb < NT; ++kb) {
        const int buf = kb & 1;
        const unsigned short* sK  = sKV[buf];
        const unsigned short* sVt = sKV[buf] + 4096;

        if (kb + 1 < NT) {  // prefetch next tile into other buffer
            const char* nimg = img + (size_t)(kb + 1) * 16384;
            char* dst = (char*)sKV[buf ^ 1];
            #pragma unroll
            for (int c = 0; c < 4; ++c)
                gld16(nimg + woff + c * 1024 + loff, dst + woff + c * 1024);
        }

        // ---- S^T = K.Q^T for this wave's 32-key half; kf feeds both subtiles
        f32x16 c0, c1;
        #pragma unroll
        for (int i = 0; i < 16; ++i) { c0[i] = 0.f; c1[i] = 0.f; }
        #pragma unroll
        for (int kc = 0; kc < 4; ++kc) {
            const bf16x8 kf = *reinterpret_cast<const bf16x8*>(
                &sK[(mtw * 4 + kc) * 512 + lane * 8]);
            c0 = __builtin_amdgcn_mfma_f32_32x32x16_bf16(kf, qf[0][kc], c0, 0, 0, 0);
            c1 = __builtin_amdgcn_mfma_f32_32x32x16_bf16(kf, qf[1][kc], c1, 0, 0, 0);
        }

        // ---- p = exp2(s), per-lane rowsum (col=q=lo32), pack to bf16 pairs
        // pk[u][rg] covers local keys 8rg+4h+0..3
        uint2 pk[2][4];
        #pragma unroll
        for (int u = 0; u < 2; ++u) {
            #pragma unroll
            for (int rg = 0; rg < 4; ++rg) {
                const float s0 = u ? c1[4 * rg + 0] : c0[4 * rg + 0];
                const float s1 = u ? c1[4 * rg + 1] : c0[4 * rg + 1];
                const float s2 = u ? c1[4 * rg + 2] : c0[4 * rg + 2];
                const float s3 = u ? c1[4 * rg + 3] : c0[4 * rg + 3];
                const float p0 = EXP2(s0), p1 = EXP2(s1), p2 = EXP2(s2), p3 = EXP2(s3);
                rsum[u] += (p0 + p1) + (p2 + p3);
                pk[u][rg].x = packbf2(p0, p1);
                pk[u][rg].y = packbf2(p2, p3);
            }
        }

        // ---- PV over this wave's 32 keys: 2 chunks of K=16
        // Lane (q,h) needs A[j] = P[q][16kcp+8h+j]: own group pk[2kcp+h],
        // partner's pk[2kcp+h] via shfl_xor(32) (partner sends pk[2kcp+1-h]).
        #pragma unroll
        for (int kcp = 0; kcp < 2; ++kcp) {
            const int kv = mtw * 2 + kcp;  // global 16-key chunk 0..3
            const bf16x8 vf0 = *reinterpret_cast<const bf16x8*>(
                &sVt[(0 + kv) * 512 + lane * 8]);
            const bf16x8 vf1 = *reinterpret_cast<const bf16x8*>(
                &sVt[(4 + kv) * 512 + lane * 8]);
            #pragma unroll
            for (int u = 0; u < 2; ++u) {
                const uint2 own = h ? pk[u][2 * kcp + 1] : pk[u][2 * kcp];
                const uint2 prv = h ? pk[u][2 * kcp]     : pk[u][2 * kcp + 1];
                uint2 rec;
                rec.x = (unsigned)__shfl_xor((int)prv.x, 32);
                rec.y = (unsigned)__shfl_xor((int)prv.y, 32);
                u4bf8 a4;
                a4.u.x = h ? rec.x : own.x;
                a4.u.y = h ? rec.y : own.y;
                a4.u.z = h ? own.x : rec.x;
                a4.u.w = h ? own.y : rec.y;
                accO[u][0] = __builtin_amdgcn_mfma_f32_32x32x16_bf16(a4.v, vf0, accO[u][0], 0, 0, 0);
                accO[u][1] = __builtin_amdgcn_mfma_f32_32x32x16_bf16(a4.v, vf1, accO[u][1], 0, 0, 0);
            }
        }
        __syncthreads();  // buf readers done + prefetch DMA drained
    }

    // ---- epilogue: combine the two key-half waves of each q-pair -------------
    float rhalf[2];
    #pragma unroll
    for (int u = 0; u < 2; ++u) rhalf[u] = rsum[u] + __shfl_xor(rsum[u], 32);

    float* sF = (float*)sKV;   // 32 KB scratch, safe after final barrier
    if (mtw == 1) {
        if (h == 0) { sR[qp2][0][lo32] = rhalf[0]; sR[qp2][1][lo32] = rhalf[1]; }
        #pragma unroll
        for (int u = 0; u < 2; ++u)
            #pragma unroll
            for (int nt = 0; nt < 2; ++nt)
                #pragma unroll
                for (int rq = 0; rq < 4; ++rq) {
                    float4 v;
                    v.x = accO[u][nt][4 * rq + 0];
                    v.y = accO[u][nt][4 * rq + 1];
                    v.z = accO[u][nt][4 * rq + 2];
                    v.w = accO[u][nt][4 * rq + 3];
                    *reinterpret_cast<float4*>(
                        &sF[qp2 * 4096 + (u * 2 + nt) * 1024 + rq * 256 + lane * 4]) = v;
                }
    }
    __syncthreads();
    if (mtw == 0) {
        // FIX: per-q inverse must be looked up by the element's q-ROW (accO's
        // lane index lo32 is d, not q). Publish 1/total at index q=lo32, then
        // read sInv[...][row] per element (row depends only on h -> broadcast).
        #pragma unroll
        for (int u = 0; u < 2; ++u)
            sInv[qp2][u][lo32] = 1.0f / (rhalf[u] + sR[qp2][u][lo32]);
        #pragma unroll
        for (int u = 0; u < 2; ++u) {
            #pragma unroll
            for (int nt = 0; nt < 2; ++nt) {
                #pragma unroll
                for (int rq = 0; rq < 4; ++rq) {
                    const float4 p = *reinterpret_cast<const float4*>(
                        &sF[qp2 * 4096 + (u * 2 + nt) * 1024 + rq * 256 + lane * 4]);
                    const float pa[4] = {p.x, p.y, p.z, p.w};
                    #pragma unroll
                    for (int i = 0; i < 4; ++i) {
                        const int row = i + 8 * rq + 4 * h;
                        gO[(size_t)(qblk * BM + qp2 * 64 + u * 32 + row) * Dh + nt * 32 + lo32] =
                            (accO[u][nt][4 * rq + i] + pa[i]) * sInv[qp2][u][row];
                    }
                }
            }
        }
    }
}

// ---------------- fallback (round-1 proven kernel) if ws is too small --------
constexpr int LD = 72;
__global__ __launch_bounds__(256, 2)
void fattn_fallback(const float* __restrict__ Q, const float* __restrict__ K,
                    const float* __restrict__ V, float* __restrict__ O)
{
    __shared__ unsigned short sK [BN * LD];
    __shared__ unsigned short sVt[Dh * LD];
    __shared__ unsigned short sP [4 * 16 * LD];

    const int tid  = threadIdx.x;
    const int wave = tid >> 6;
    const int lane = tid & 63;
    const int lo   = lane & 15;
    const int quad = lane >> 4;
    const int qblk = blockIdx.x;
    const int bh   = blockIdx.y;

    const float* gQ = Q + (size_t)bh * Sseq * Dh;
    const float* gK = K + (size_t)bh * Sseq * Dh;
    const float* gV = V + (size_t)bh * Sseq * Dh;
    float*       gO = O + (size_t)bh * Sseq * Dh;

    const float qscale = 0.18033688011112042f;
    bf16x8 qf[2];
    {
        const int qrow = qblk * 64 + wave * 16 + lo;
        const float* qp = gQ + (size_t)qrow * Dh + quad * 8;
        #pragma unroll
        for (int c = 0; c < 2; ++c) {
            float4 a = *reinterpret_cast<const float4*>(qp + c * 32);
            float4 b = *reinterpret_cast<const float4*>(qp + c * 32 + 4);
            qf[c][0] = (short)f2bf(a.x * qscale); qf[c][1] = (short)f2bf(a.y * qscale);
            qf[c][2] = (short)f2bf(a.z * qscale); qf[c][3] = (short)f2bf(a.w * qscale);
            qf[c][4] = (short)f2bf(b.x * qscale); qf[c][5] = (short)f2bf(b.y * qscale);
            qf[c][6] = (short)f2bf(b.z * qscale); qf[c][7] = (short)f2bf(b.w * qscale);
        }
    }

    float m_prev[4] = {-1e30f, -1e30f, -1e30f, -1e30f};
    float lsum[4]   = {0.f, 0.f, 0.f, 0.f};
    f32x4 accv[4];
    #pragma unroll
    for (int t = 0; t < 4; ++t) accv[t] = f32x4{0.f, 0.f, 0.f, 0.f};
    unsigned short* sPw = &sP[wave * 16 * LD];

    for (int kb = 0; kb < Sseq / BN; ++kb) {
        const float4* k4 = reinterpret_cast<const float4*>(gK + (size_t)kb * BN * Dh);
        const float4* v4 = reinterpret_cast<const float4*>(gV + (size_t)kb * BN * Dh);
        #pragma unroll
        for (int it = 0; it < 4; ++it) {
            const int f   = it * 256 + tid;
            const int row = f >> 4;
            const int c4  = (f & 15) * 4;
            float4 kv = k4[f];
            unsigned int l32 = (unsigned int)f2bf(kv.x) | ((unsigned int)f2bf(kv.y) << 16);
            unsigned int h32 = (unsigned int)f2bf(kv.z) | ((unsigned int)f2bf(kv.w) << 16);
            *reinterpret_cast<uint2*>(&sK[row * LD + c4]) = make_uint2(l32, h32);
            float4 vv = v4[f];
            sVt[(c4 + 0) * LD + row] = f2bf(vv.x);
            sVt[(c4 + 1) * LD + row] = f2bf(vv.y);
            sVt[(c4 + 2) * LD + row] = f2bf(vv.z);
            sVt[(c4 + 3) * LD + row] = f2bf(vv.w);
        }
        __syncthreads();

        float sc[4][4];
        #pragma unroll
        for (int t = 0; t < 4; ++t) {
            const bf16x8 k0 = *reinterpret_cast<const bf16x8*>(&sK[(t * 16 + lo) * LD + 0  + quad * 8]);
            const bf16x8 k1 = *reinterpret_cast<const bf16x8*>(&sK[(t * 16 + lo) * LD + 32 + quad * 8]);
            f32x4 s = f32x4{0.f, 0.f, 0.f, 0.f};
            s = __builtin_amdgcn_mfma_f32_16x16x32_bf16(qf[0], k0, s, 0, 0, 0);
            s = __builtin_amdgcn_mfma_f32_16x16x32_bf16(qf[1], k1, s, 0, 0, 0);
            sc[t][0] = s[0]; sc[t][1] = s[1]; sc[t][2] = s[2]; sc[t][3] = s[3];
        }

        float bm[4];
        #pragma unroll
        for (int r = 0; r < 4; ++r)
            bm[r] = fmaxf(fmaxf(sc[0][r], sc[1][r]), fmaxf(sc[2][r], sc[3][r]));
        #pragma unroll
        for (int m = 1; m <= 8; m <<= 1) {
            #pragma unroll
            for (int r = 0; r < 4; ++r) bm[r] = fmaxf(bm[r], __shfl_xor(bm[r], m));
        }
        float m_new[4], alpha[4];
        #pragma unroll
        for (int r = 0; r < 4; ++r) {
            m_new[r] = fmaxf(m_prev[r], bm[r]);
            alpha[r] = exp2f(m_prev[r] - m_new[r]);
            m_prev[r] = m_new[r];
        }
        float ps[4][4];
        float rs[4] = {0.f, 0.f, 0.f, 0.f};
        #pragma unroll
        for (int t = 0; t < 4; ++t) {
            #pragma unroll
            for (int r = 0; r < 4; ++r) { ps[t][r] = exp2f(sc[t][r] - m_new[r]); rs[r] += ps[t][r]; }
        }
        #pragma unroll
        for (int m = 1; m <= 8; m <<= 1) {
            #pragma unroll
            for (int r = 0; r < 4; ++r) rs[r] += __shfl_xor(rs[r], m);
        }
        #pragma unroll
        for (int r = 0; r < 4; ++r) lsum[r] = lsum[r] * alpha[r] + rs[r];
        #pragma unroll
        for (int t = 0; t < 4; ++t) {
            #pragma unroll
            for (int r = 0; r < 4; ++r) accv[t][r] *= alpha[r];
        }
        #pragma unroll
        for (int t = 0; t < 4; ++t) {
            #pragma unroll
            for (int r = 0; r < 4; ++r)
                sPw[(quad * 4 + r) * LD + t * 16 + lo] = f2bf(ps[t][r]);
        }
        #pragma unroll
        for (int c = 0; c < 2; ++c) {
            const bf16x8 af = *reinterpret_cast<const bf16x8*>(&sPw[lo * LD + c * 32 + quad * 8]);
            #pragma unroll
            for (int t2 = 0; t2 < 4; ++t2) {
                const bf16x8 vf = *reinterpret_cast<const bf16x8*>(&sVt[(t2 * 16 + lo) * LD + c * 32 + quad * 8]);
                accv[t2] = __builtin_amdgcn_mfma_f32_16x16x32_bf16(af, vf, accv[t2], 0, 0, 0);
            }
        }
        __syncthreads();
    }

    const int qbase = qblk * 64 + wave * 16 + quad * 4;
    #pragma unroll
    for (int r = 0; r < 4; ++r) {
        const float inv = 1.0f / lsum[r];
        float* op = gO + (size_t)(qbase + r) * Dh;
        #pragma unroll
        for (int t2 = 0; t2 < 4; ++t2)
            op[t2 * 16 + lo] = accv[t2][r] * inv;
    }
}

extern "C" void kernel_launch(void* const* d_in, const int* in_sizes, int n_in,
                              void* d_out, int out_size, void* d_ws, size_t ws_size,
                              hipStream_t stream) {
    const float* Q = (const float*)d_in[0];
    const float* K = (const float*)d_in[1];
    const float* V = (const float*)d_in[2];
    float* O = (float*)d_out;
    const int BH = in_sizes[0] / (Sseq * Dh);  // 24
    const size_t ws_needed = (size_t)BH * NT * 16384;  // 25.2 MB
    if (ws_size >= ws_needed) {
        preconv_kernel<<<dim3(NT, BH), 256, 0, stream>>>(K, V, (unsigned short*)d_ws);
        fattn_kernel<<<dim3(Sseq / BM, BH), 256, 0, stream>>>(Q, (const unsigned short*)d_ws, O);
    } else {
        fattn_fallback<<<dim3(Sseq / 64, BH), 256, 0, stream>>>(Q, K, V, O);
    }
}

// Round 8
// 268.739 us; speedup vs baseline: 1.1388x; 1.1388x over previous
//
#include <hip/hip_runtime.h>

// Scaled dot-product attention, B=2 H=12 S=4096 d=64, fp32 in/out.
// Round 8: split-K waves (wave = q-pair x key-half) with WAVE-PRIVATE P LDS
// round-trip (no cross-half shfl exchange -- R7's exchange cost more VALU than
// it saved). kf/vf fragments shared across 2 q-subtiles; fragment-ordered
// conflict-free K/V images (R7, measured 0 conflicts); 4 independent waves,
// 12 waves/CU. preconv: coalesced loads, K scatter-stores, V LDS transpose.
// Layouts (m74/m101, verified rounds 3-7):
//  A 32x32x16: A[m=lane&31][k=8*(lane>>5)+j]; B: B[k=8*(lane>>5)+j][n=lane&31]
//  C/D: col=lane&31, row=(reg&3)+8*(reg>>2)+4*(lane>>5)

constexpr int Sseq = 4096;
constexpr int Dh   = 64;
constexpr int BM   = 128;         // q rows per block (2 q-pairs x 2 subtiles x 32)
constexpr int BN   = 64;          // keys per K-tile (2 kh waves x 32)
constexpr int NT   = Sseq / BN;   // 64 key-tiles per head

typedef short bf16x8 __attribute__((ext_vector_type(8)));
typedef float f32x4  __attribute__((ext_vector_type(4)));
typedef float f32x16 __attribute__((ext_vector_type(16)));

__device__ __forceinline__ unsigned short f2bf(float x) {
    union { float f; unsigned int u; } v; v.f = x;
    unsigned int r = v.u + 0x7fffu + ((v.u >> 16) & 1u);  // RNE
    return (unsigned short)(r >> 16);
}

// pack two f32 -> bf16x2 (a -> low16, b -> high16), round-half-up
__device__ __forceinline__ unsigned int packbf2(float a, float b) {
    unsigned int ua = __float_as_uint(a) + 0x8000u;
    unsigned int ub = __float_as_uint(b) + 0x8000u;
    return __builtin_amdgcn_perm(ub, ua, 0x07060302u);
}

#define EXP2(x) exp2f(x)

__device__ __forceinline__ void gld16(const void* g, void* l) {
    __builtin_amdgcn_global_load_lds(
        (const __attribute__((address_space(1))) void*)g,
        (__attribute__((address_space(3))) void*)l, 16, 0, 0);
}

// ---------------- pre-pass: fragment-ordered bf16 images ---------------------
// ws per (bh,kb): 16 chunks x 1024 B. Chunks 0-7 = K, 8-15 = V^T.
// K chunk (mt*4+kc), lane slot l: K[key=32mt+(l&31)][d=16kc+8*(l>>5)+0..7]
// V chunk 8+(nt*4+kv), lane slot l: V^T[d=32nt+(l&31)][key=16kv+8*(l>>5)+0..7]
__global__ __launch_bounds__(256)
void preconv_kernel(const float* __restrict__ K, const float* __restrict__ V,
                    unsigned short* __restrict__ ws)
{
    __shared__ unsigned short tV[64 * 72];   // [d][key], padded stride 72
    const int kb = blockIdx.x, bh = blockIdx.y, tid = threadIdx.x;
    const float4* k4 = reinterpret_cast<const float4*>(K + ((size_t)bh * Sseq + kb * BN) * Dh);
    const float4* v4 = reinterpret_cast<const float4*>(V + ((size_t)bh * Sseq + kb * BN) * Dh);
    unsigned short* kimg = ws + (size_t)(bh * NT + kb) * 8192;
    unsigned short* vimg = kimg + 4096;

    // batch ALL loads first (coalesced float4)
    float4 kv[4], vv[4];
    #pragma unroll
    for (int it = 0; it < 4; ++it) kv[it] = k4[it * 256 + tid];
    #pragma unroll
    for (int it = 0; it < 4; ++it) vv[it] = v4[it * 256 + tid];

    #pragma unroll
    for (int it = 0; it < 4; ++it) {
        const int f  = it * 256 + tid;
        const int key = f >> 4;          // 0..63
        const int c4  = (f & 15) * 4;    // 0..60
        // K: scatter 8B store into fragment-order image (loads were coalesced)
        const int chunk = (key >> 5) * 4 + (c4 >> 4);
        const int ln    = ((c4 >> 3) & 1) * 32 + (key & 31);
        uint2 p;
        p.x = packbf2(kv[it].x, kv[it].y);
        p.y = packbf2(kv[it].z, kv[it].w);
        *reinterpret_cast<uint2*>(&kimg[chunk * 512 + ln * 8 + (c4 & 7)]) = p;
        // V: transpose into LDS
        tV[(c4 + 0) * 72 + key] = f2bf(vv[it].x);
        tV[(c4 + 1) * 72 + key] = f2bf(vv[it].y);
        tV[(c4 + 2) * 72 + key] = f2bf(vv[it].z);
        tV[(c4 + 3) * 72 + key] = f2bf(vv[it].w);
    }
    __syncthreads();
    // frag-order copy-out, coalesced uint4 stores
    #pragma unroll
    for (int i = 0; i < 2; ++i) {
        const int c = i * 256 + tid;           // slot 0..511
        const int chv = c >> 6, l = c & 63;    // V chunk 0..7
        const int d    = 32 * (chv >> 2) + (l & 31);
        const int key0 = 16 * (chv & 3) + 8 * (l >> 5);
        const uint4 x = *reinterpret_cast<const uint4*>(&tV[d * 72 + key0]);
        *reinterpret_cast<uint4*>(&vimg[c * 8]) = x;
    }
}

// ---------------- main flash-attention kernel --------------------------------
__global__ __launch_bounds__(256, 3)
void fattn_kernel(const float* __restrict__ Q, const unsigned short* __restrict__ ws,
                  float* __restrict__ O)
{
    __shared__ unsigned short sKV[2][8192];       // dbuf: [K 8KB | V^T 8KB], frag order
    __shared__ unsigned short sP[2][2][2][1024];  // [qp][kh][u]: P frag-order (2KB)
    __shared__ float sR[2][2][32];                // cross-kh rowsum exchange
    __shared__ float sInv[2][2][32];              // per-q inverse (epilogue)

    const int tid  = threadIdx.x;
    const int wave = tid >> 6;
    const int lane = tid & 63;
    const int lo32 = lane & 31;
    const int h    = lane >> 5;   // half-wave 0/1
    const int qp   = wave >> 1;   // q-pair 0/1 (q rows qp*64 .. +63)
    const int kh   = wave & 1;    // key-half 0/1 (keys kh*32 .. +31)

    const int qblk = blockIdx.x;  // 0..31
    const int bh   = blockIdx.y;  // 0..23

    const float* gQ = Q + (size_t)bh * Sseq * Dh;
    float*       gO = O + (size_t)bh * Sseq * Dh;

    // Q as B-operand of S^T = K.Q^T: lane holds Q[q=lo32][d = 16kc + 8h + j]
    const float qscale = 0.18033688011112042f;  // (1/sqrt(64)) * log2(e)
    bf16x8 qf[2][4];
    #pragma unroll
    for (int u = 0; u < 2; ++u) {
        const int qrow = qblk * BM + qp * 64 + u * 32 + lo32;
        const float* qptr = gQ + (size_t)qrow * Dh + h * 8;
        #pragma unroll
        for (int kc = 0; kc < 4; ++kc) {
            float4 a = *reinterpret_cast<const float4*>(qptr + kc * 16);
            float4 b = *reinterpret_cast<const float4*>(qptr + kc * 16 + 4);
            qf[u][kc][0] = (short)f2bf(a.x * qscale);
            qf[u][kc][1] = (short)f2bf(a.y * qscale);
            qf[u][kc][2] = (short)f2bf(a.z * qscale);
            qf[u][kc][3] = (short)f2bf(a.w * qscale);
            qf[u][kc][4] = (short)f2bf(b.x * qscale);
            qf[u][kc][5] = (short)f2bf(b.y * qscale);
            qf[u][kc][6] = (short)f2bf(b.z * qscale);
            qf[u][kc][7] = (short)f2bf(b.w * qscale);
        }
    }

    f32x16 accO[2][2];   // [subtile][d-half]; partial over this wave's 32 keys
    #pragma unroll
    for (int u = 0; u < 2; ++u)
        #pragma unroll
        for (int nt = 0; nt < 2; ++nt)
            #pragma unroll
            for (int i = 0; i < 16; ++i) accO[u][nt][i] = 0.f;
    float rsum[2] = {0.f, 0.f};  // per-lane, q=lo32, rows of parity h

    unsigned short* sP0 = &sP[qp][kh][0][0];
    unsigned short* sP1 = &sP[qp][kh][1][0];
    const char* img = (const char*)(ws + (size_t)bh * NT * 8192);
    const int loff = lane * 16;
    const int woff = wave * 4096;

    // prologue: DMA tile 0 -> buf 0 (each wave stages 4 KB)
    #pragma unroll
    for (int c = 0; c < 4; ++c)
        gld16(img + woff + c * 1024 + loff, (char*)sKV[0] + woff + c * 1024);
    __syncthreads();

    for (int kb = 0; kb < NT; ++kb) {
        const int buf = kb & 1;
        const unsigned short* sK  = sKV[buf];
        const unsigned short* sVt = sKV[buf] + 4096;

        if (kb + 1 < NT) {  // prefetch next tile into other buffer
            const char* nimg = img + (size_t)(kb + 1) * 16384;
            char* dst = (char*)sKV[buf ^ 1];
            #pragma unroll
            for (int c = 0; c < 4; ++c)
                gld16(nimg + woff + c * 1024 + loff, dst + woff + c * 1024);
        }

        // ---- S^T = K.Q^T for this wave's 32-key half; kf feeds both subtiles
        f32x16 c0, c1;
        #pragma unroll
        for (int i = 0; i < 16; ++i) { c0[i] = 0.f; c1[i] = 0.f; }
        #pragma unroll
        for (int kc = 0; kc < 4; ++kc) {
            const bf16x8 kf = *reinterpret_cast<const bf16x8*>(
                &sK[(kh * 4 + kc) * 512 + lane * 8]);
            c0 = __builtin_amdgcn_mfma_f32_32x32x16_bf16(kf, qf[0][kc], c0, 0, 0, 0);
            c1 = __builtin_amdgcn_mfma_f32_32x32x16_bf16(kf, qf[1][kc], c1, 0, 0, 0);
        }

        // ---- p = exp2(s); per-lane rowsum (q=lo32); pack; write wave-private P
        // C rows (local key) = (reg&3)+8*(reg>>2)+4h; regs 4rg..4rg+3 = keys 8rg+4h+0..3
        // P dest (A-frag order, chunk kcp): slot l holds P[q=l&31][16kcp+8*(l>>5)+0..7]
        //   4-key group g=2rg+h -> kcp=rg>>1, half=rg&1, in-slot off=h*4
        #pragma unroll
        for (int u = 0; u < 2; ++u) {
            unsigned short* sPu = u ? sP1 : sP0;
            #pragma unroll
            for (int rg = 0; rg < 4; ++rg) {
                const float s0 = u ? c1[4 * rg + 0] : c0[4 * rg + 0];
                const float s1 = u ? c1[4 * rg + 1] : c0[4 * rg + 1];
                const float s2 = u ? c1[4 * rg + 2] : c0[4 * rg + 2];
                const float s3 = u ? c1[4 * rg + 3] : c0[4 * rg + 3];
                const float p0 = EXP2(s0), p1 = EXP2(s1), p2 = EXP2(s2), p3 = EXP2(s3);
                rsum[u] += (p0 + p1) + (p2 + p3);
                uint2 pk;
                pk.x = packbf2(p0, p1);
                pk.y = packbf2(p2, p3);
                *reinterpret_cast<uint2*>(
                    &sPu[(rg >> 1) * 512 + (rg & 1) * 256 + lo32 * 8 + h * 4]) = pk;
            }
        }

        // ---- PV over this wave's 32 keys (kcp = two K=16 chunks); vf shared x2
        #pragma unroll
        for (int kcp = 0; kcp < 2; ++kcp) {
            const int kv = kh * 2 + kcp;  // global 16-key chunk 0..3
            const bf16x8 af0 = *reinterpret_cast<const bf16x8*>(&sP0[kcp * 512 + lane * 8]);
            const bf16x8 af1 = *reinterpret_cast<const bf16x8*>(&sP1[kcp * 512 + lane * 8]);
            #pragma unroll
            for (int nt = 0; nt < 2; ++nt) {
                const bf16x8 vf = *reinterpret_cast<const bf16x8*>(
                    &sVt[(nt * 4 + kv) * 512 + lane * 8]);
                accO[0][nt] = __builtin_amdgcn_mfma_f32_32x32x16_bf16(af0, vf, accO[0][nt], 0, 0, 0);
                accO[1][nt] = __builtin_amdgcn_mfma_f32_32x32x16_bf16(af1, vf, accO[1][nt], 0, 0, 0);
            }
        }
        __syncthreads();  // buf readers done + prefetch DMA drained
    }

    // ---- epilogue: combine the two key-half waves of each q-pair -------------
    float rhalf[2];
    #pragma unroll
    for (int u = 0; u < 2; ++u) rhalf[u] = rsum[u] + __shfl_xor(rsum[u], 32);

    float* sF = (float*)sKV;   // 32 KB scratch, safe after final barrier
    if (kh == 1) {
        if (h == 0) { sR[qp][0][lo32] = rhalf[0]; sR[qp][1][lo32] = rhalf[1]; }
        #pragma unroll
        for (int u = 0; u < 2; ++u)
            #pragma unroll
            for (int nt = 0; nt < 2; ++nt)
                #pragma unroll
                for (int rq = 0; rq < 4; ++rq) {
                    float4 v;
                    v.x = accO[u][nt][4 * rq + 0];
                    v.y = accO[u][nt][4 * rq + 1];
                    v.z = accO[u][nt][4 * rq + 2];
                    v.w = accO[u][nt][4 * rq + 3];
                    *reinterpret_cast<float4*>(
                        &sF[qp * 4096 + (u * 2 + nt) * 1024 + rq * 256 + lane * 4]) = v;
                }
    }
    __syncthreads();
    if (kh == 0) {
        // inverse indexed by q: publish at q=lo32, read per element by its q-ROW
        #pragma unroll
        for (int u = 0; u < 2; ++u)
            sInv[qp][u][lo32] = 1.0f / (rhalf[u] + sR[qp][u][lo32]);
        #pragma unroll
        for (int u = 0; u < 2; ++u) {
            #pragma unroll
            for (int nt = 0; nt < 2; ++nt) {
                #pragma unroll
                for (int rq = 0; rq < 4; ++rq) {
                    const float4 p = *reinterpret_cast<const float4*>(
                        &sF[qp * 4096 + (u * 2 + nt) * 1024 + rq * 256 + lane * 4]);
                    const float pa[4] = {p.x, p.y, p.z, p.w};
                    #pragma unroll
                    for (int i = 0; i < 4; ++i) {
                        const int row = i + 8 * rq + 4 * h;
                        gO[(size_t)(qblk * BM + qp * 64 + u * 32 + row) * Dh + nt * 32 + lo32] =
                            (accO[u][nt][4 * rq + i] + pa[i]) * sInv[qp][u][row];
                    }
                }
            }
        }
    }
}

// ---------------- fallback (round-1 proven kernel) if ws is too small --------
constexpr int LD = 72;
__global__ __launch_bounds__(256, 2)
void fattn_fallback(const float* __restrict__ Q, const float* __restrict__ K,
                    const float* __restrict__ V, float* __restrict__ O)
{
    __shared__ unsigned short sK [BN * LD];
    __shared__ unsigned short sVt[Dh * LD];
    __shared__ unsigned short sP [4 * 16 * LD];

    const int tid  = threadIdx.x;
    const int wave = tid >> 6;
    const int lane = tid & 63;
    const int lo   = lane & 15;
    const int quad = lane >> 4;
    const int qblk = blockIdx.x;
    const int bh   = blockIdx.y;

    const float* gQ = Q + (size_t)bh * Sseq * Dh;
    const float* gK = K + (size_t)bh * Sseq * Dh;
    const float* gV = V + (size_t)bh * Sseq * Dh;
    float*       gO = O + (size_t)bh * Sseq * Dh;

    const float qscale = 0.18033688011112042f;
    bf16x8 qf[2];
    {
        const int qrow = qblk * 64 + wave * 16 + lo;
        const float* qp = gQ + (size_t)qrow * Dh + quad * 8;
        #pragma unroll
        for (int c = 0; c < 2; ++c) {
            float4 a = *reinterpret_cast<const float4*>(qp + c * 32);
            float4 b = *reinterpret_cast<const float4*>(qp + c * 32 + 4);
            qf[c][0] = (short)f2bf(a.x * qscale); qf[c][1] = (short)f2bf(a.y * qscale);
            qf[c][2] = (short)f2bf(a.z * qscale); qf[c][3] = (short)f2bf(a.w * qscale);
            qf[c][4] = (short)f2bf(b.x * qscale); qf[c][5] = (short)f2bf(b.y * qscale);
            qf[c][6] = (short)f2bf(b.z * qscale); qf[c][7] = (short)f2bf(b.w * qscale);
        }
    }

    float m_prev[4] = {-1e30f, -1e30f, -1e30f, -1e30f};
    float lsum[4]   = {0.f, 0.f, 0.f, 0.f};
    f32x4 accv[4];
    #pragma unroll
    for (int t = 0; t < 4; ++t) accv[t] = f32x4{0.f, 0.f, 0.f, 0.f};
    unsigned short* sPw = &sP[wave * 16 * LD];

    for (int kb = 0; kb < Sseq / BN; ++kb) {
        const float4* k4 = reinterpret_cast<const float4*>(gK + (size_t)kb * BN * Dh);
        const float4* v4 = reinterpret_cast<const float4*>(gV + (size_t)kb * BN * Dh);
        #pragma unroll
        for (int it = 0; it < 4; ++it) {
            const int f   = it * 256 + tid;
            const int row = f >> 4;
            const int c4  = (f & 15) * 4;
            float4 kv = k4[f];
            unsigned int l32 = (unsigned int)f2bf(kv.x) | ((unsigned int)f2bf(kv.y) << 16);
            unsigned int h32 = (unsigned int)f2bf(kv.z) | ((unsigned int)f2bf(kv.w) << 16);
            *reinterpret_cast<uint2*>(&sK[row * LD + c4]) = make_uint2(l32, h32);
            float4 vv = v4[f];
            sVt[(c4 + 0) * LD + row] = f2bf(vv.x);
            sVt[(c4 + 1) * LD + row] = f2bf(vv.y);
            sVt[(c4 + 2) * LD + row] = f2bf(vv.z);
            sVt[(c4 + 3) * LD + row] = f2bf(vv.w);
        }
        __syncthreads();

        float sc[4][4];
        #pragma unroll
        for (int t = 0; t < 4; ++t) {
            const bf16x8 k0 = *reinterpret_cast<const bf16x8*>(&sK[(t * 16 + lo) * LD + 0  + quad * 8]);
            const bf16x8 k1 = *reinterpret_cast<const bf16x8*>(&sK[(t * 16 + lo) * LD + 32 + quad * 8]);
            f32x4 s = f32x4{0.f, 0.f, 0.f, 0.f};
            s = __builtin_amdgcn_mfma_f32_16x16x32_bf16(qf[0], k0, s, 0, 0, 0);
            s = __builtin_amdgcn_mfma_f32_16x16x32_bf16(qf[1], k1, s, 0, 0, 0);
            sc[t][0] = s[0]; sc[t][1] = s[1]; sc[t][2] = s[2]; sc[t][3] = s[3];
        }

        float bm[4];
        #pragma unroll
        for (int r = 0; r < 4; ++r)
            bm[r] = fmaxf(fmaxf(sc[0][r], sc[1][r]), fmaxf(sc[2][r], sc[3][r]));
        #pragma unroll
        for (int m = 1; m <= 8; m <<= 1) {
            #pragma unroll
            for (int r = 0; r < 4; ++r) bm[r] = fmaxf(bm[r], __shfl_xor(bm[r], m));
        }
        float m_new[4], alpha[4];
        #pragma unroll
        for (int r = 0; r < 4; ++r) {
            m_new[r] = fmaxf(m_prev[r], bm[r]);
            alpha[r] = exp2f(m_prev[r] - m_new[r]);
            m_prev[r] = m_new[r];
        }
        float ps[4][4];
        float rs[4] = {0.f, 0.f, 0.f, 0.f};
        #pragma unroll
        for (int t = 0; t < 4; ++t) {
            #pragma unroll
            for (int r = 0; r < 4; ++r) { ps[t][r] = exp2f(sc[t][r] - m_new[r]); rs[r] += ps[t][r]; }
        }
        #pragma unroll
        for (int m = 1; m <= 8; m <<= 1) {
            #pragma unroll
            for (int r = 0; r < 4; ++r) rs[r] += __shfl_xor(rs[r], m);
        }
        #pragma unroll
        for (int r = 0; r < 4; ++r) lsum[r] = lsum[r] * alpha[r] + rs[r];
        #pragma unroll
        for (int t = 0; t < 4; ++t) {
            #pragma unroll
            for (int r = 0; r < 4; ++r) accv[t][r] *= alpha[r];
        }
        #pragma unroll
        for (int t = 0; t < 4; ++t) {
            #pragma unroll
            for (int r = 0; r < 4; ++r)
                sPw[(quad * 4 + r) * LD + t * 16 + lo] = f2bf(ps[t][r]);
        }
        #pragma unroll
        for (int c = 0; c < 2; ++c) {
            const bf16x8 af = *reinterpret_cast<const bf16x8*>(&sPw[lo * LD + c * 32 + quad * 8]);
            #pragma unroll
            for (int t2 = 0; t2 < 4; ++t2) {
                const bf16x8 vf = *reinterpret_cast<const bf16x8*>(&sVt[(t2 * 16 + lo) * LD + c * 32 + quad * 8]);
                accv[t2] = __builtin_amdgcn_mfma_f32_16x16x32_bf16(af, vf, accv[t2], 0, 0, 0);
            }
        }
        __syncthreads();
    }

    const int qbase = qblk * 64 + wave * 16 + quad * 4;
    #pragma unroll
    for (int r = 0; r < 4; ++r) {
        const float inv = 1.0f / lsum[r];
        float* op = gO + (size_t)(qbase + r) * Dh;
        #pragma unroll
        for (int t2 = 0; t2 < 4; ++t2)
            op[t2 * 16 + lo] = accv[t2][r] * inv;
    }
}

extern "C" void kernel_launch(void* const* d_in, const int* in_sizes, int n_in,
                              void* d_out, int out_size, void* d_ws, size_t ws_size,
                              hipStream_t stream) {
    const float* Q = (const float*)d_in[0];
    const float* K = (const float*)d_in[1];
    const float* V = (const float*)d_in[2];
    float* O = (float*)d_out;
    const int BH = in_sizes[0] / (Sseq * Dh);  // 24
    const size_t ws_needed = (size_t)BH * NT * 16384;  // 25.2 MB
    if (ws_size >= ws_needed) {
        preconv_kernel<<<dim3(NT, BH), 256, 0, stream>>>(K, V, (unsigned short*)d_ws);
        fattn_kernel<<<dim3(Sseq / BM, BH), 256, 0, stream>>>(Q, (const unsigned short*)d_ws, O);
    } else {
        fattn_fallback<<<dim3(Sseq / 64, BH), 256, 0, stream>>>(Q, K, V, O);
    }
}